// Round 1
// baseline (4833.449 us; speedup 1.0000x reference)
//
#include <hip/hip_runtime.h>
#include <math.h>

#define NB 256
#define LM 16
#define HID 512
#define H4 2048
#define D2 1024
#define D5 5120
#define KC 32
#define NPAIR0 3840   // 256*15
#define CHUNK 512

__device__ __forceinline__ float sigm(float x) { return 1.0f / (1.0f + expf(-x)); }

// ---------------------------------------------------------------------------
// init: zero LSTM state, identity slot maps, iter-0 rowlist (all 15 pairs/batch)
// rowlist entry: {batch, slotL, slotR, cslot | (plog<<16)}; batch<0 => invalid
// ---------------------------------------------------------------------------
__global__ __launch_bounds__(256)
void init_kernel(float* hcur, float* ccur, int* pos, int* pair, int4* rowlist)
{
    int b = blockIdx.x, tid = threadIdx.x;
    for (int u = tid; u < HID; u += 256) {
        hcur[(size_t)b * HID + u] = 0.f;
        hcur[((size_t)NB + b) * HID + u] = 0.f;
        ccur[(size_t)b * HID + u] = 0.f;
        ccur[((size_t)NB + b) * HID + u] = 0.f;
    }
    if (tid < 16) { pos[b * 16 + tid] = tid; pair[b * 16 + tid] = tid; }
    if (tid < 15) rowlist[b * 15 + tid] = make_int4(b, tid, tid + 1, tid | (tid << 16));
}

// ---------------------------------------------------------------------------
// LSTM step GEMM: g[dir][b][j] = sum_k [x_row | h_cur] * [w_ih | w_hh]^T
// 64x64 tile, K=1024 in chunks of 32, fp32.
// ---------------------------------------------------------------------------
__global__ __launch_bounds__(256)
void gemm_lstm(int t, const float* __restrict__ x, const int* __restrict__ lengths,
               const float* __restrict__ w_ih_f, const float* __restrict__ w_hh_f,
               const float* __restrict__ w_ih_b, const float* __restrict__ w_hh_b,
               const float* __restrict__ hcur, float* __restrict__ g_buf)
{
    const int dir = blockIdx.z;
    const float* w_ih = dir ? w_ih_b : w_ih_f;
    const float* w_hh = dir ? w_hh_b : w_hh_f;
    const int row0 = blockIdx.y * 64;
    const int col0 = blockIdx.x * 64;
    const int tid = threadIdx.x;
    const int tx = tid & 15, ty = tid >> 4;
    const int lr = tid & 63, lk = tid >> 6;

    __shared__ float Xs[KC][68];
    __shared__ float Ws[KC][68];

    const int b = row0 + lr;
    const int len = lengths[b];
    const int trow = (dir == 0) ? t : ((t < len) ? (len - 1 - t) : t);
    const float* px = x + ((size_t)b * LM + trow) * HID;
    const float* ph = hcur + ((size_t)dir * NB + b) * HID;
    const int j = col0 + lr;

    float acc[4][4] = {{0.f}};

    for (int k0 = 0; k0 < 1024; k0 += KC) {
        const float* xs = ((k0 < HID) ? (px + k0) : (ph + (k0 - HID))) + lk * 8;
        float4 a0 = *(const float4*)(xs);
        float4 a1 = *(const float4*)(xs + 4);
        const float* wsrc = ((k0 < HID) ? (w_ih + (size_t)j * HID + k0)
                                        : (w_hh + (size_t)j * HID + (k0 - HID))) + lk * 8;
        float4 b0 = *(const float4*)(wsrc);
        float4 b1 = *(const float4*)(wsrc + 4);
        Xs[lk*8+0][lr]=a0.x; Xs[lk*8+1][lr]=a0.y; Xs[lk*8+2][lr]=a0.z; Xs[lk*8+3][lr]=a0.w;
        Xs[lk*8+4][lr]=a1.x; Xs[lk*8+5][lr]=a1.y; Xs[lk*8+6][lr]=a1.z; Xs[lk*8+7][lr]=a1.w;
        Ws[lk*8+0][lr]=b0.x; Ws[lk*8+1][lr]=b0.y; Ws[lk*8+2][lr]=b0.z; Ws[lk*8+3][lr]=b0.w;
        Ws[lk*8+4][lr]=b1.x; Ws[lk*8+5][lr]=b1.y; Ws[lk*8+6][lr]=b1.z; Ws[lk*8+7][lr]=b1.w;
        __syncthreads();
#pragma unroll
        for (int kk = 0; kk < KC; ++kk) {
            float4 xa = *(const float4*)&Xs[kk][ty * 4];
            float4 wb = *(const float4*)&Ws[kk][tx * 4];
            acc[0][0] += xa.x*wb.x; acc[0][1] += xa.x*wb.y; acc[0][2] += xa.x*wb.z; acc[0][3] += xa.x*wb.w;
            acc[1][0] += xa.y*wb.x; acc[1][1] += xa.y*wb.y; acc[1][2] += xa.y*wb.z; acc[1][3] += xa.y*wb.w;
            acc[2][0] += xa.z*wb.x; acc[2][1] += xa.z*wb.y; acc[2][2] += xa.z*wb.z; acc[2][3] += xa.z*wb.w;
            acc[3][0] += xa.w*wb.x; acc[3][1] += xa.w*wb.y; acc[3][2] += xa.w*wb.z; acc[3][3] += xa.w*wb.w;
        }
        __syncthreads();
    }
    for (int i = 0; i < 4; ++i) {
        int bb = row0 + ty * 4 + i;
        float4 v4 = make_float4(acc[i][0], acc[i][1], acc[i][2], acc[i][3]);
        *(float4*)(g_buf + ((size_t)(dir * NB + bb)) * H4 + col0 + tx * 4) = v4;
    }
}

// ---------------------------------------------------------------------------
// LSTM gates: c = sig(f)c + sig(i)tanh(u); h = sig(o)tanh(c); scatter to seq.
// ---------------------------------------------------------------------------
__global__ __launch_bounds__(256)
void lstm_gate(int t, const int* __restrict__ lengths,
               const float* __restrict__ b_f, const float* __restrict__ b_b,
               const float* __restrict__ g_buf,
               float* __restrict__ hcur, float* __restrict__ ccur,
               float* __restrict__ h_seq, float* __restrict__ c_seq)
{
    int b = blockIdx.x, dir = blockIdx.y, tid = threadIdx.x;
    const float* bias = dir ? b_b : b_f;
    int len = lengths[b];
    int pos = dir ? ((t < len) ? (len - 1 - t) : t) : t;
    const float* g = g_buf + ((size_t)(dir * NB + b)) * H4;
    float* hc = hcur + ((size_t)(dir * NB + b)) * HID;
    float* cc = ccur + ((size_t)(dir * NB + b)) * HID;
    float* hs = h_seq + ((size_t)(b * LM + pos)) * D2 + dir * HID;
    float* cs = c_seq + ((size_t)(b * LM + pos)) * D2 + dir * HID;
    for (int u = tid; u < HID; u += 256) {
        float gi = g[u]           + bias[u];
        float gf = g[HID + u]     + bias[HID + u];
        float gu = g[2 * HID + u] + bias[2 * HID + u];
        float go = g[3 * HID + u] + bias[3 * HID + u];
        float c = sigm(gf) * cc[u] + sigm(gi) * tanhf(gu);
        float h = sigm(go) * tanhf(c);
        cc[u] = c; hc[u] = h;
        hs[u] = h; cs[u] = c;
    }
}

// ---------------------------------------------------------------------------
// Pair GEMM: v[r][0..5119] = [h(slotL) | h(slotR)] @ w_comp^T  (K = 2048)
// ---------------------------------------------------------------------------
__global__ __launch_bounds__(256)
void gemm_pairs(const int4* __restrict__ rowlist, int nrows,
                const float* __restrict__ h_seq,
                const float* __restrict__ w_comp,
                float* __restrict__ v_buf)
{
    const int row0 = blockIdx.y * 64;
    if (row0 >= nrows) return;
    const int col0 = blockIdx.x * 64;
    const int tid = threadIdx.x;
    const int tx = tid & 15, ty = tid >> 4;
    const int lr = tid & 63, lk = tid >> 6;

    __shared__ float Xs[KC][68];
    __shared__ float Ws[KC][68];

    int grow = row0 + lr;
    int4 e = (grow < nrows) ? rowlist[grow] : make_int4(-1, 0, 0, 0);
    const float* pL;
    const float* pR;
    if (e.x >= 0) {
        pL = h_seq + ((size_t)(e.x * LM + e.y)) * D2;
        pR = h_seq + ((size_t)(e.x * LM + e.z)) * D2;
    } else { pL = h_seq; pR = h_seq; }
    const int j = col0 + lr;

    float acc[4][4] = {{0.f}};

    for (int k0 = 0; k0 < 2048; k0 += KC) {
        const float* xs = ((k0 < D2) ? (pL + k0) : (pR + (k0 - D2))) + lk * 8;
        float4 a0 = *(const float4*)(xs);
        float4 a1 = *(const float4*)(xs + 4);
        const float* wsrc = w_comp + ((size_t)j) * 2048 + k0 + lk * 8;
        float4 b0 = *(const float4*)(wsrc);
        float4 b1 = *(const float4*)(wsrc + 4);
        Xs[lk*8+0][lr]=a0.x; Xs[lk*8+1][lr]=a0.y; Xs[lk*8+2][lr]=a0.z; Xs[lk*8+3][lr]=a0.w;
        Xs[lk*8+4][lr]=a1.x; Xs[lk*8+5][lr]=a1.y; Xs[lk*8+6][lr]=a1.z; Xs[lk*8+7][lr]=a1.w;
        Ws[lk*8+0][lr]=b0.x; Ws[lk*8+1][lr]=b0.y; Ws[lk*8+2][lr]=b0.z; Ws[lk*8+3][lr]=b0.w;
        Ws[lk*8+4][lr]=b1.x; Ws[lk*8+5][lr]=b1.y; Ws[lk*8+6][lr]=b1.z; Ws[lk*8+7][lr]=b1.w;
        __syncthreads();
#pragma unroll
        for (int kk = 0; kk < KC; ++kk) {
            float4 xa = *(const float4*)&Xs[kk][ty * 4];
            float4 wb = *(const float4*)&Ws[kk][tx * 4];
            acc[0][0] += xa.x*wb.x; acc[0][1] += xa.x*wb.y; acc[0][2] += xa.x*wb.z; acc[0][3] += xa.x*wb.w;
            acc[1][0] += xa.y*wb.x; acc[1][1] += xa.y*wb.y; acc[1][2] += xa.y*wb.z; acc[1][3] += xa.y*wb.w;
            acc[2][0] += xa.z*wb.x; acc[2][1] += xa.z*wb.y; acc[2][2] += xa.z*wb.z; acc[2][3] += xa.z*wb.w;
            acc[3][0] += xa.w*wb.x; acc[3][1] += xa.w*wb.y; acc[3][2] += xa.w*wb.z; acc[3][3] += xa.w*wb.w;
        }
        __syncthreads();
    }
    for (int i = 0; i < 4; ++i) {
        int r = row0 + ty * 4 + i;
        if (r < nrows) {
            int4 e2 = rowlist[r];
            if (e2.x >= 0) {
                float4 v4 = make_float4(acc[i][0], acc[i][1], acc[i][2], acc[i][3]);
                *(float4*)(v_buf + (size_t)r * D5 + col0 + tx * 4) = v4;
            }
        }
    }
}

// ---------------------------------------------------------------------------
// TreeLSTM gates + logit: one block per rowlist entry.
// ---------------------------------------------------------------------------
__global__ __launch_bounds__(256)
void gates_logits(const int4* __restrict__ rowlist, int nrows,
                  const float* __restrict__ v_buf, const float* __restrict__ b_comp,
                  const float* __restrict__ c_seq, const float* __restrict__ w_q,
                  float* __restrict__ nh_cand, float* __restrict__ nc_cand,
                  float* __restrict__ logits)
{
    int row = blockIdx.x;
    if (row >= nrows) return;
    int4 e = rowlist[row];
    if (e.x < 0) return;
    int b = e.x, sL = e.y, sR = e.z;
    int cslot = e.w & 0xffff, plog = e.w >> 16;
    const float* v = v_buf + (size_t)row * D5;
    const float* cl = c_seq + ((size_t)(b * LM + sL)) * D2;
    const float* cr = c_seq + ((size_t)(b * LM + sR)) * D2;
    float* nh = nh_cand + ((size_t)(b * 15 + cslot)) * D2;
    float* nc = nc_cand + ((size_t)(b * 15 + cslot)) * D2;

    float part = 0.f;
    for (int d = threadIdx.x; d < D2; d += 256) {
        float gi  = v[d]          + b_comp[d];
        float gfl = v[D2 + d]     + b_comp[D2 + d];
        float gfr = v[2 * D2 + d] + b_comp[2 * D2 + d];
        float gu  = v[3 * D2 + d] + b_comp[3 * D2 + d];
        float go  = v[4 * D2 + d] + b_comp[4 * D2 + d];
        float c = cl[d] * sigm(gfl + 1.0f) + cr[d] * sigm(gfr + 1.0f) + tanhf(gu) * sigm(gi);
        float h = sigm(go) * tanhf(c);
        nc[d] = c; nh[d] = h;
        part += h * w_q[d];
    }
    for (int o = 32; o > 0; o >>= 1) part += __shfl_down(part, o);
    __shared__ float wsum[4];
    if ((threadIdx.x & 63) == 0) wsum[threadIdx.x >> 6] = part;
    __syncthreads();
    if (threadIdx.x == 0) logits[b * 16 + plog] = wsum[0] + wsum[1] + wsum[2] + wsum[3];
}

// ---------------------------------------------------------------------------
// Merge: masked first-max argmax, apply candidate, update slot maps,
// emit rowlist of the <=2 pairs needing recompute.
// ---------------------------------------------------------------------------
__global__ __launch_bounds__(256)
void merge_kernel(int iter, const int* __restrict__ lengths,
                  float* __restrict__ h_seq, float* __restrict__ c_seq,
                  const float* __restrict__ nh_cand, const float* __restrict__ nc_cand,
                  float* __restrict__ logits, int* __restrict__ pos_idx,
                  int* __restrict__ pair_idx, int4* __restrict__ rowlist)
{
    int b = blockIdx.x, tid = threadIdx.x;
    int M = 15 - iter;  // current pair count
    int len = lengths[b];
    bool done = (iter + 1) < len;

    __shared__ float sl[16];
    __shared__ int sp[16], sq[16];
    __shared__ int s_sel;

    if (tid <= M) sp[tid] = pos_idx[b * 16 + tid];
    if (tid < M) { sq[tid] = pair_idx[b * 16 + tid]; sl[tid] = logits[b * 16 + tid]; }
    __syncthreads();

    if (tid == 0) {
        int sel = -1;
        if (done) {
            float best = -INFINITY; sel = 0;
            for (int p = 0; p < M; ++p) {
                float mv = ((iter + 1 + p) < len) ? sl[p] : (sl[p] - 10000.0f);
                if (mv > best) { best = mv; sel = p; }
            }
        }
        s_sel = sel;
    }
    __syncthreads();
    int sel = s_sel;

    if (sel >= 0) {
        int slotL = sp[sel];
        int cslot = sq[sel];
        const float* nh = nh_cand + ((size_t)(b * 15 + cslot)) * D2;
        const float* nc = nc_cand + ((size_t)(b * 15 + cslot)) * D2;
        float* hd = h_seq + ((size_t)(b * LM + slotL)) * D2;
        float* cd = c_seq + ((size_t)(b * LM + slotL)) * D2;
        for (int d = tid; d < D2; d += 256) { hd[d] = nh[d]; cd[d] = nc[d]; }

        if (tid == 0) {
            // remove position sel+1 (M+1 -> M entries)
            for (int p = sel + 1; p < M; ++p) sp[p] = sp[p + 1];
            // pairs: new[p] = old[p+1] for p > sel (M -> M-1 entries)
            for (int p = sel + 1; p < M - 1; ++p) { sq[p] = sq[p + 1]; sl[p] = sl[p + 1]; }
            int Mn = M - 1;
            if (iter < 14) {
                int4 inv = make_int4(-1, 0, 0, 0);
                int4 e0 = inv, e1 = inv;
                if (sel - 1 >= 0)
                    e0 = make_int4(b, sp[sel - 1], sp[sel], sq[sel - 1] | ((sel - 1) << 16));
                if (sel <= Mn - 1)
                    e1 = make_int4(b, sp[sel], sp[sel + 1], sq[sel] | (sel << 16));
                rowlist[2 * b] = e0;
                rowlist[2 * b + 1] = e1;
            }
            for (int p = 0; p < M; ++p) pos_idx[b * 16 + p] = sp[p];
            for (int p = 0; p < Mn; ++p) { pair_idx[b * 16 + p] = sq[p]; logits[b * 16 + p] = sl[p]; }
        }
    } else {
        if (tid == 0 && iter < 14) {
            rowlist[2 * b] = make_int4(-1, 0, 0, 0);
            rowlist[2 * b + 1] = make_int4(-1, 0, 0, 0);
        }
    }
}

__global__ __launch_bounds__(256)
void copy_out(const float* __restrict__ h_seq, float* __restrict__ out)
{
    int b = blockIdx.x;
    for (int d = threadIdx.x; d < D2; d += 256)
        out[(size_t)b * D2 + d] = h_seq[((size_t)(b * LM)) * D2 + d];
}

// ---------------------------------------------------------------------------
extern "C" void kernel_launch(void* const* d_in, const int* in_sizes, int n_in,
                              void* d_out, int out_size, void* d_ws, size_t ws_size,
                              hipStream_t stream)
{
    const float* x      = (const float*)d_in[0];
    const int*   lens   = (const int*)  d_in[1];
    const float* w_ih_f = (const float*)d_in[2];
    const float* w_hh_f = (const float*)d_in[3];
    const float* b_f    = (const float*)d_in[4];
    const float* w_ih_b = (const float*)d_in[5];
    const float* w_hh_b = (const float*)d_in[6];
    const float* b_b    = (const float*)d_in[7];
    const float* w_comp = (const float*)d_in[8];
    const float* b_comp = (const float*)d_in[9];
    const float* w_q    = (const float*)d_in[10];
    float* out = (float*)d_out;

    char* p = (char*)d_ws;
    float* h_seq = (float*)p; p += (size_t)NB * LM * D2 * 4;
    float* c_seq = (float*)p; p += (size_t)NB * LM * D2 * 4;
    float* nh    = (float*)p; p += (size_t)NB * 15 * D2 * 4;
    float* nc    = (float*)p; p += (size_t)NB * 15 * D2 * 4;
    float* vbuf  = (float*)p; p += (size_t)CHUNK * D5 * 4;
    float* gbuf  = (float*)p; p += (size_t)2 * NB * H4 * 4;
    float* hcur  = (float*)p; p += (size_t)2 * NB * HID * 4;
    float* ccur  = (float*)p; p += (size_t)2 * NB * HID * 4;
    float* logits= (float*)p; p += (size_t)NB * 16 * 4;
    int*   pos   = (int*)p;   p += (size_t)NB * 16 * 4;
    int*   pair  = (int*)p;   p += (size_t)NB * 16 * 4;
    int4*  rowlist = (int4*)p; p += (size_t)NPAIR0 * 16;

    hipLaunchKernelGGL(init_kernel, dim3(NB), dim3(256), 0, stream,
                       hcur, ccur, pos, pair, rowlist);

    // ---- bidirectional LSTM, 16 sequential steps ----
    for (int t = 0; t < 16; ++t) {
        hipLaunchKernelGGL(gemm_lstm, dim3(32, 4, 2), dim3(256), 0, stream,
                           t, x, lens, w_ih_f, w_hh_f, w_ih_b, w_hh_b, hcur, gbuf);
        hipLaunchKernelGGL(lstm_gate, dim3(NB, 2), dim3(256), 0, stream,
                           t, lens, b_f, b_b, gbuf, hcur, ccur, h_seq, c_seq);
    }

    // ---- iter 0: candidates + logits for all 15 pairs (chunked) ----
    for (int c = 0; c < 8; ++c) {
        int off = c * CHUNK;
        int rows = NPAIR0 - off; if (rows > CHUNK) rows = CHUNK;
        hipLaunchKernelGGL(gemm_pairs, dim3(80, 8), dim3(256), 0, stream,
                           rowlist + off, rows, h_seq, w_comp, vbuf);
        hipLaunchKernelGGL(gates_logits, dim3(CHUNK), dim3(256), 0, stream,
                           rowlist + off, rows, vbuf, b_comp, c_seq, w_q, nh, nc, logits);
    }

    // ---- 14 selection iterations + final merge ----
    for (int it = 0; it < 14; ++it) {
        hipLaunchKernelGGL(merge_kernel, dim3(NB), dim3(256), 0, stream,
                           it, lens, h_seq, c_seq, nh, nc, logits, pos, pair, rowlist);
        hipLaunchKernelGGL(gemm_pairs, dim3(80, 8), dim3(256), 0, stream,
                           rowlist, 2 * NB, h_seq, w_comp, vbuf);
        hipLaunchKernelGGL(gates_logits, dim3(2 * NB), dim3(256), 0, stream,
                           rowlist, 2 * NB, vbuf, b_comp, c_seq, w_q, nh, nc, logits);
    }
    hipLaunchKernelGGL(merge_kernel, dim3(NB), dim3(256), 0, stream,
                       14, lens, h_seq, c_seq, nh, nc, logits, pos, pair, rowlist);

    hipLaunchKernelGGL(copy_out, dim3(NB), dim3(256), 0, stream, h_seq, out);
}

// Round 2
// 2599.991 us; speedup vs baseline: 1.8590x; 1.8590x over previous
//
#include <hip/hip_runtime.h>
#include <math.h>

#define NB 256
#define LM 16
#define HID 512
#define H4 2048
#define D2 1024
#define D5 5120
#define KC 32
#define NPAIR0 3840   // 256*15
#define ASTR 40       // LDS row stride in shorts (32 data + 8 pad, 80B, 16B-aligned)
#define BSTR 40

typedef __attribute__((ext_vector_type(8))) short bf16x8;
typedef __attribute__((ext_vector_type(4))) float f32x4;

__device__ __forceinline__ float sigm(float x) { return 1.0f / (1.0f + expf(-x)); }

__device__ __forceinline__ unsigned short bf16_rne(float f) {
    union { float f; unsigned u; } v; v.f = f;
    unsigned u = v.u;
    return (unsigned short)((u + 0x7fffu + ((u >> 16) & 1u)) >> 16);
}
__device__ __forceinline__ float bf16_tof(unsigned short h) {
    union { unsigned u; float f; } v; v.u = ((unsigned)h) << 16;
    return v.f;
}

// ---------------------------------------------------------------------------
// init: zero LSTM state, identity slot maps, iter-0 rowlist, zero compaction
// counters. rowlist entry: {batch, slotL, slotR, cslot | (plog<<16)}
// ---------------------------------------------------------------------------
__global__ __launch_bounds__(256)
void init_kernel(float* hcur, float* ccur, int* pos, int* pair, int4* rowlist0,
                 int* rcount)
{
    int b = blockIdx.x, tid = threadIdx.x;
    for (int u = tid; u < HID; u += 256) {
        hcur[(size_t)b * HID + u] = 0.f;
        hcur[((size_t)NB + b) * HID + u] = 0.f;
        ccur[(size_t)b * HID + u] = 0.f;
        ccur[((size_t)NB + b) * HID + u] = 0.f;
    }
    if (tid < 16) { pos[b * 16 + tid] = tid; pair[b * 16 + tid] = tid; }
    if (tid < 15) rowlist0[b * 15 + tid] = make_int4(b, tid, tid + 1, tid | (tid << 16));
    if (b == 0 && tid < 16) rcount[tid] = 0;
}

// ---------------------------------------------------------------------------
// Split w_comp (5120x2048 fp32) into hi/lo bf16 planes. 2.62M float4s.
// ---------------------------------------------------------------------------
__global__ __launch_bounds__(256)
void split_w(const float4* __restrict__ w, unsigned short* __restrict__ hi,
             unsigned short* __restrict__ lo, int n4)
{
    for (int i = blockIdx.x * 256 + threadIdx.x; i < n4; i += gridDim.x * 256) {
        float4 f = w[i];
        ushort4 h, l;
        h.x = bf16_rne(f.x); l.x = bf16_rne(f.x - bf16_tof(h.x));
        h.y = bf16_rne(f.y); l.y = bf16_rne(f.y - bf16_tof(h.y));
        h.z = bf16_rne(f.z); l.z = bf16_rne(f.z - bf16_tof(h.z));
        h.w = bf16_rne(f.w); l.w = bf16_rne(f.w - bf16_tof(h.w));
        ((ushort4*)hi)[i] = h;
        ((ushort4*)lo)[i] = l;
    }
}

// ---------------------------------------------------------------------------
// LSTM step GEMM (fp32, unchanged from round 1 — ~0.5ms total, not the
// bottleneck yet).
// ---------------------------------------------------------------------------
__global__ __launch_bounds__(256)
void gemm_lstm(int t, const float* __restrict__ x, const int* __restrict__ lengths,
               const float* __restrict__ w_ih_f, const float* __restrict__ w_hh_f,
               const float* __restrict__ w_ih_b, const float* __restrict__ w_hh_b,
               const float* __restrict__ hcur, float* __restrict__ g_buf)
{
    const int dir = blockIdx.z;
    const float* w_ih = dir ? w_ih_b : w_ih_f;
    const float* w_hh = dir ? w_hh_b : w_hh_f;
    const int row0 = blockIdx.y * 64;
    const int col0 = blockIdx.x * 64;
    const int tid = threadIdx.x;
    const int tx = tid & 15, ty = tid >> 4;
    const int lr = tid & 63, lk = tid >> 6;

    __shared__ float Xs[KC][68];
    __shared__ float Ws[KC][68];

    const int b = row0 + lr;
    const int len = lengths[b];
    const int trow = (dir == 0) ? t : ((t < len) ? (len - 1 - t) : t);
    const float* px = x + ((size_t)b * LM + trow) * HID;
    const float* ph = hcur + ((size_t)dir * NB + b) * HID;
    const int j = col0 + lr;

    float acc[4][4] = {{0.f}};

    for (int k0 = 0; k0 < 1024; k0 += KC) {
        const float* xs = ((k0 < HID) ? (px + k0) : (ph + (k0 - HID))) + lk * 8;
        float4 a0 = *(const float4*)(xs);
        float4 a1 = *(const float4*)(xs + 4);
        const float* wsrc = ((k0 < HID) ? (w_ih + (size_t)j * HID + k0)
                                        : (w_hh + (size_t)j * HID + (k0 - HID))) + lk * 8;
        float4 b0 = *(const float4*)(wsrc);
        float4 b1 = *(const float4*)(wsrc + 4);
        Xs[lk*8+0][lr]=a0.x; Xs[lk*8+1][lr]=a0.y; Xs[lk*8+2][lr]=a0.z; Xs[lk*8+3][lr]=a0.w;
        Xs[lk*8+4][lr]=a1.x; Xs[lk*8+5][lr]=a1.y; Xs[lk*8+6][lr]=a1.z; Xs[lk*8+7][lr]=a1.w;
        Ws[lk*8+0][lr]=b0.x; Ws[lk*8+1][lr]=b0.y; Ws[lk*8+2][lr]=b0.z; Ws[lk*8+3][lr]=b0.w;
        Ws[lk*8+4][lr]=b1.x; Ws[lk*8+5][lr]=b1.y; Ws[lk*8+6][lr]=b1.z; Ws[lk*8+7][lr]=b1.w;
        __syncthreads();
#pragma unroll
        for (int kk = 0; kk < KC; ++kk) {
            float4 xa = *(const float4*)&Xs[kk][ty * 4];
            float4 wb = *(const float4*)&Ws[kk][tx * 4];
            acc[0][0] += xa.x*wb.x; acc[0][1] += xa.x*wb.y; acc[0][2] += xa.x*wb.z; acc[0][3] += xa.x*wb.w;
            acc[1][0] += xa.y*wb.x; acc[1][1] += xa.y*wb.y; acc[1][2] += xa.y*wb.z; acc[1][3] += xa.y*wb.w;
            acc[2][0] += xa.z*wb.x; acc[2][1] += xa.z*wb.y; acc[2][2] += xa.z*wb.z; acc[2][3] += xa.z*wb.w;
            acc[3][0] += xa.w*wb.x; acc[3][1] += xa.w*wb.y; acc[3][2] += xa.w*wb.z; acc[3][3] += xa.w*wb.w;
        }
        __syncthreads();
    }
    for (int i = 0; i < 4; ++i) {
        int bb = row0 + ty * 4 + i;
        float4 v4 = make_float4(acc[i][0], acc[i][1], acc[i][2], acc[i][3]);
        *(float4*)(g_buf + ((size_t)(dir * NB + bb)) * H4 + col0 + tx * 4) = v4;
    }
}

// ---------------------------------------------------------------------------
// LSTM gates; h written as split bf16 (hi/lo) for the MFMA pair-GEMM.
// ---------------------------------------------------------------------------
__global__ __launch_bounds__(256)
void lstm_gate(int t, const int* __restrict__ lengths,
               const float* __restrict__ b_f, const float* __restrict__ b_b,
               const float* __restrict__ g_buf,
               float* __restrict__ hcur, float* __restrict__ ccur,
               unsigned short* __restrict__ h_hi, unsigned short* __restrict__ h_lo,
               float* __restrict__ c_seq)
{
    int b = blockIdx.x, dir = blockIdx.y, tid = threadIdx.x;
    const float* bias = dir ? b_b : b_f;
    int len = lengths[b];
    int pos = dir ? ((t < len) ? (len - 1 - t) : t) : t;
    const float* g = g_buf + ((size_t)(dir * NB + b)) * H4;
    float* hc = hcur + ((size_t)(dir * NB + b)) * HID;
    float* cc = ccur + ((size_t)(dir * NB + b)) * HID;
    unsigned short* hh = h_hi + ((size_t)(b * LM + pos)) * D2 + dir * HID;
    unsigned short* hl = h_lo + ((size_t)(b * LM + pos)) * D2 + dir * HID;
    float* cs = c_seq + ((size_t)(b * LM + pos)) * D2 + dir * HID;
    for (int u = tid; u < HID; u += 256) {
        float gi = g[u]           + bias[u];
        float gf = g[HID + u]     + bias[HID + u];
        float gu = g[2 * HID + u] + bias[2 * HID + u];
        float go = g[3 * HID + u] + bias[3 * HID + u];
        float c = sigm(gf) * cc[u] + sigm(gi) * tanhf(gu);
        float h = sigm(go) * tanhf(c);
        cc[u] = c; hc[u] = h; cs[u] = c;
        unsigned short hb = bf16_rne(h);
        hh[u] = hb;
        hl[u] = bf16_rne(h - bf16_tof(hb));
    }
}

// ---------------------------------------------------------------------------
// Pair GEMM, bf16x3 MFMA: V[r][j] = sum_k X[r][k] * W[j][k], K=2048.
// X = [h(slotL) | h(slotR)] as hi+lo bf16 planes; 3 passes hi*hi+hi*lo+lo*hi.
// Block: 256 thr = 4 waves (2x2), tile 64 rows x 128 cols, K-step 32.
// nrows from literal or device counter (compacted rowlist).
// ---------------------------------------------------------------------------
__global__ __launch_bounds__(256)
void gemm_pairs_mfma(const int4* __restrict__ rowlist, int nrows_lit,
                     const int* __restrict__ nrows_ptr,
                     const unsigned short* __restrict__ h_hi,
                     const unsigned short* __restrict__ h_lo,
                     const unsigned short* __restrict__ w_hi,
                     const unsigned short* __restrict__ w_lo,
                     float* __restrict__ vbuf)
{
    int nrows = nrows_ptr ? *nrows_ptr : nrows_lit;
    const int row0 = blockIdx.x * 64;
    if (row0 >= nrows) return;
    const int col0 = blockIdx.y * 128;
    const int tid = threadIdx.x;
    const int lane = tid & 63;
    const int wid = tid >> 6;
    const int wm = wid >> 1, wn = wid & 1;

    __shared__ unsigned short As[2][64 * ASTR];
    __shared__ unsigned short Bs[2][128 * BSTR];

    // A staging: 4 threads per row (16B each of hi and lo per K-step)
    const int arow = tid >> 2, apart = tid & 3;
    int rr = row0 + arow; if (rr > nrows - 1) rr = nrows - 1;
    int4 e = rowlist[rr];
    if (e.x < 0) { e.x = 0; e.y = 0; e.z = 1; }
    const unsigned short* aLh = h_hi + ((size_t)(e.x * LM + e.y)) * D2;
    const unsigned short* aLl = h_lo + ((size_t)(e.x * LM + e.y)) * D2;
    const unsigned short* aRh = h_hi + ((size_t)(e.x * LM + e.z)) * D2;
    const unsigned short* aRl = h_lo + ((size_t)(e.x * LM + e.z)) * D2;

    // B staging: 2 threads per col; each does 2x16B of hi and of lo
    const int bcol = tid >> 1, bhalf = tid & 1;
    const unsigned short* wh = w_hi + ((size_t)(col0 + bcol)) * H4;
    const unsigned short* wl = w_lo + ((size_t)(col0 + bcol)) * H4;

    f32x4 acc[2][4];
#pragma unroll
    for (int i = 0; i < 2; ++i)
#pragma unroll
        for (int j = 0; j < 4; ++j) acc[i][j] = (f32x4){0.f, 0.f, 0.f, 0.f};

    // fragment read offsets (in shorts): A row = wm*32+fm*16+(lane&15),
    // k-part = (lane>>4)*8 ; B col = wn*64+fn*16+(lane&15)
    const int a_off0 = (wm * 32 + (lane & 15)) * ASTR + (lane >> 4) * 8;
    const int a_off1 = a_off0 + 16 * ASTR;
    const int b_off0 = (wn * 64 + (lane & 15)) * BSTR + (lane >> 4) * 8;

    for (int k0 = 0; k0 < H4; k0 += 32) {
        const unsigned short* sh  = (k0 < D2) ? (aLh + k0) : (aRh + (k0 - D2));
        const unsigned short* sl2 = (k0 < D2) ? (aLl + k0) : (aRl + (k0 - D2));
        uint4 gAh  = *(const uint4*)(sh  + apart * 8);
        uint4 gAl  = *(const uint4*)(sl2 + apart * 8);
        uint4 gBh0 = *(const uint4*)(wh + k0 + (bhalf * 2 + 0) * 8);
        uint4 gBh1 = *(const uint4*)(wh + k0 + (bhalf * 2 + 1) * 8);
        uint4 gBl0 = *(const uint4*)(wl + k0 + (bhalf * 2 + 0) * 8);
        uint4 gBl1 = *(const uint4*)(wl + k0 + (bhalf * 2 + 1) * 8);
        __syncthreads();
        *(uint4*)&As[0][arow * ASTR + apart * 8] = gAh;
        *(uint4*)&As[1][arow * ASTR + apart * 8] = gAl;
        *(uint4*)&Bs[0][bcol * BSTR + (bhalf * 2 + 0) * 8] = gBh0;
        *(uint4*)&Bs[0][bcol * BSTR + (bhalf * 2 + 1) * 8] = gBh1;
        *(uint4*)&Bs[1][bcol * BSTR + (bhalf * 2 + 0) * 8] = gBl0;
        *(uint4*)&Bs[1][bcol * BSTR + (bhalf * 2 + 1) * 8] = gBl1;
        __syncthreads();

        bf16x8 a0h = *(const bf16x8*)&As[0][a_off0];
        bf16x8 a0l = *(const bf16x8*)&As[1][a_off0];
        bf16x8 a1h = *(const bf16x8*)&As[0][a_off1];
        bf16x8 a1l = *(const bf16x8*)&As[1][a_off1];
#pragma unroll
        for (int fn = 0; fn < 4; ++fn) {
            bf16x8 bh = *(const bf16x8*)&Bs[0][b_off0 + fn * 16 * BSTR];
            bf16x8 bl = *(const bf16x8*)&Bs[1][b_off0 + fn * 16 * BSTR];
            acc[0][fn] = __builtin_amdgcn_mfma_f32_16x16x32_bf16(a0h, bh, acc[0][fn], 0, 0, 0);
            acc[0][fn] = __builtin_amdgcn_mfma_f32_16x16x32_bf16(a0h, bl, acc[0][fn], 0, 0, 0);
            acc[0][fn] = __builtin_amdgcn_mfma_f32_16x16x32_bf16(a0l, bh, acc[0][fn], 0, 0, 0);
            acc[1][fn] = __builtin_amdgcn_mfma_f32_16x16x32_bf16(a1h, bh, acc[1][fn], 0, 0, 0);
            acc[1][fn] = __builtin_amdgcn_mfma_f32_16x16x32_bf16(a1h, bl, acc[1][fn], 0, 0, 0);
            acc[1][fn] = __builtin_amdgcn_mfma_f32_16x16x32_bf16(a1l, bh, acc[1][fn], 0, 0, 0);
        }
    }

    // epilogue: C/D layout col=lane&15, row=(lane>>4)*4+q
#pragma unroll
    for (int fm = 0; fm < 2; ++fm) {
        int rbase = row0 + wm * 32 + fm * 16 + (lane >> 4) * 4;
#pragma unroll
        for (int fn = 0; fn < 4; ++fn) {
            int c = col0 + wn * 64 + fn * 16 + (lane & 15);
#pragma unroll
            for (int q = 0; q < 4; ++q) {
                int r = rbase + q;
                if (r < nrows) vbuf[(size_t)r * D5 + c] = acc[fm][fn][q];
            }
        }
    }
}

// ---------------------------------------------------------------------------
// TreeLSTM gates + logit: one block per rowlist entry.
// ---------------------------------------------------------------------------
__global__ __launch_bounds__(256)
void gates_logits(const int4* __restrict__ rowlist, int nrows_lit,
                  const int* __restrict__ nrows_ptr,
                  const float* __restrict__ v_buf, const float* __restrict__ b_comp,
                  const float* __restrict__ c_seq, const float* __restrict__ w_q,
                  float* __restrict__ nh_cand, float* __restrict__ nc_cand,
                  float* __restrict__ logits)
{
    int nrows = nrows_ptr ? *nrows_ptr : nrows_lit;
    int row = blockIdx.x;
    if (row >= nrows) return;
    int4 e = rowlist[row];
    if (e.x < 0) return;
    int b = e.x, sL = e.y, sR = e.z;
    int cslot = e.w & 0xffff, plog = e.w >> 16;
    const float* v = v_buf + (size_t)row * D5;
    const float* cl = c_seq + ((size_t)(b * LM + sL)) * D2;
    const float* cr = c_seq + ((size_t)(b * LM + sR)) * D2;
    float* nh = nh_cand + ((size_t)(b * 15 + cslot)) * D2;
    float* nc = nc_cand + ((size_t)(b * 15 + cslot)) * D2;

    float part = 0.f;
    for (int d = threadIdx.x; d < D2; d += 256) {
        float gi  = v[d]          + b_comp[d];
        float gfl = v[D2 + d]     + b_comp[D2 + d];
        float gfr = v[2 * D2 + d] + b_comp[2 * D2 + d];
        float gu  = v[3 * D2 + d] + b_comp[3 * D2 + d];
        float go  = v[4 * D2 + d] + b_comp[4 * D2 + d];
        float c = cl[d] * sigm(gfl + 1.0f) + cr[d] * sigm(gfr + 1.0f) + tanhf(gu) * sigm(gi);
        float h = sigm(go) * tanhf(c);
        nc[d] = c; nh[d] = h;
        part += h * w_q[d];
    }
    for (int o = 32; o > 0; o >>= 1) part += __shfl_down(part, o);
    __shared__ float wsum[4];
    if ((threadIdx.x & 63) == 0) wsum[threadIdx.x >> 6] = part;
    __syncthreads();
    if (threadIdx.x == 0) logits[b * 16 + plog] = wsum[0] + wsum[1] + wsum[2] + wsum[3];
}

// ---------------------------------------------------------------------------
// Merge: argmax, apply candidate (write split h), update slot maps, emit
// COMPACTED rowlist of pairs needing recompute via atomic counter.
// ---------------------------------------------------------------------------
__global__ __launch_bounds__(256)
void merge_kernel(int iter, const int* __restrict__ lengths,
                  float* __restrict__ c_seq,
                  const float* __restrict__ nh_cand, const float* __restrict__ nc_cand,
                  float* __restrict__ logits, int* __restrict__ pos_idx,
                  int* __restrict__ pair_idx, int4* __restrict__ rowlist_out,
                  int* __restrict__ rcount,
                  unsigned short* __restrict__ h_hi, unsigned short* __restrict__ h_lo)
{
    int b = blockIdx.x, tid = threadIdx.x;
    int M = 15 - iter;
    int len = lengths[b];
    bool act = (iter + 1) < len;

    __shared__ float sl[16];
    __shared__ int sp[16], sq[16];
    __shared__ int s_sel;

    if (tid <= M) sp[tid] = pos_idx[b * 16 + tid];
    if (tid < M) { sq[tid] = pair_idx[b * 16 + tid]; sl[tid] = logits[b * 16 + tid]; }
    __syncthreads();

    if (tid == 0) {
        int sel = -1;
        if (act) {
            float best = -INFINITY; sel = 0;
            for (int p2 = 0; p2 < M; ++p2) {
                float mv = ((iter + 1 + p2) < len) ? sl[p2] : (sl[p2] - 10000.0f);
                if (mv > best) { best = mv; sel = p2; }
            }
        }
        s_sel = sel;
    }
    __syncthreads();
    int sel = s_sel;

    if (sel >= 0) {
        int slotL = sp[sel];
        int cslot = sq[sel];
        const float* nh = nh_cand + ((size_t)(b * 15 + cslot)) * D2;
        const float* nc = nc_cand + ((size_t)(b * 15 + cslot)) * D2;
        float* cd = c_seq + ((size_t)(b * LM + slotL)) * D2;
        unsigned short* hh = h_hi + ((size_t)(b * LM + slotL)) * D2;
        unsigned short* hl = h_lo + ((size_t)(b * LM + slotL)) * D2;
        for (int d = tid; d < D2; d += 256) {
            float hv = nh[d];
            cd[d] = nc[d];
            unsigned short hb = bf16_rne(hv);
            hh[d] = hb;
            hl[d] = bf16_rne(hv - bf16_tof(hb));
        }

        if (tid == 0) {
            for (int p2 = sel + 1; p2 < M; ++p2) sp[p2] = sp[p2 + 1];
            for (int p2 = sel + 1; p2 < M - 1; ++p2) { sq[p2] = sq[p2 + 1]; sl[p2] = sl[p2 + 1]; }
            int Mn = M - 1;
            if (iter < 14) {
                if (sel - 1 >= 0) {
                    int4 e0 = make_int4(b, sp[sel - 1], sp[sel], sq[sel - 1] | ((sel - 1) << 16));
                    int i0 = atomicAdd(rcount, 1);
                    rowlist_out[i0] = e0;
                }
                if (sel <= Mn - 1) {
                    int4 e1 = make_int4(b, sp[sel], sp[sel + 1], sq[sel] | (sel << 16));
                    int i1 = atomicAdd(rcount, 1);
                    rowlist_out[i1] = e1;
                }
            }
            for (int p2 = 0; p2 < M; ++p2) pos_idx[b * 16 + p2] = sp[p2];
            for (int p2 = 0; p2 < Mn; ++p2) { pair_idx[b * 16 + p2] = sq[p2]; logits[b * 16 + p2] = sl[p2]; }
        }
    }
}

__global__ __launch_bounds__(256)
void copy_out(const unsigned short* __restrict__ h_hi,
              const unsigned short* __restrict__ h_lo, float* __restrict__ out)
{
    int b = blockIdx.x;
    size_t base = (size_t)(b * LM) * D2;
    for (int d = threadIdx.x; d < D2; d += 256)
        out[(size_t)b * D2 + d] = bf16_tof(h_hi[base + d]) + bf16_tof(h_lo[base + d]);
}

// ---------------------------------------------------------------------------
extern "C" void kernel_launch(void* const* d_in, const int* in_sizes, int n_in,
                              void* d_out, int out_size, void* d_ws, size_t ws_size,
                              hipStream_t stream)
{
    const float* x      = (const float*)d_in[0];
    const int*   lens   = (const int*)  d_in[1];
    const float* w_ih_f = (const float*)d_in[2];
    const float* w_hh_f = (const float*)d_in[3];
    const float* b_f    = (const float*)d_in[4];
    const float* w_ih_b = (const float*)d_in[5];
    const float* w_hh_b = (const float*)d_in[6];
    const float* b_b    = (const float*)d_in[7];
    const float* w_comp = (const float*)d_in[8];
    const float* b_comp = (const float*)d_in[9];
    const float* w_q    = (const float*)d_in[10];
    float* out = (float*)d_out;

    char* p = (char*)d_ws;
    auto alloc = [&](size_t bytes) {
        char* q = p; p += (bytes + 255) & ~(size_t)255; return q;
    };
    float* c_seq = (float*)alloc((size_t)NB * LM * D2 * 4);
    float* nh    = (float*)alloc((size_t)NB * 15 * D2 * 4);
    float* nc    = (float*)alloc((size_t)NB * 15 * D2 * 4);
    unsigned short* h_hi = (unsigned short*)alloc((size_t)NB * LM * D2 * 2);
    unsigned short* h_lo = (unsigned short*)alloc((size_t)NB * LM * D2 * 2);
    unsigned short* w_hi = (unsigned short*)alloc((size_t)D5 * H4 * 2);
    unsigned short* w_lo = (unsigned short*)alloc((size_t)D5 * H4 * 2);
    float* logits = (float*)alloc((size_t)NB * 16 * 4);
    int*   pos    = (int*)alloc((size_t)NB * 16 * 4);
    int*   pair   = (int*)alloc((size_t)NB * 16 * 4);
    int4*  rowlist0   = (int4*)alloc((size_t)NPAIR0 * 16);
    int4*  rowlist_inc= (int4*)alloc((size_t)512 * 16);
    int*   rcount = (int*)alloc(16 * 4);
    // shared tail: LSTM scratch (gbuf/hcur/ccur) then reused as vbuf
    char* shared_base = p;
    float* gbuf = (float*)shared_base;
    float* hcur = (float*)(shared_base + (size_t)2 * NB * H4 * 4);
    float* ccur = (float*)(shared_base + (size_t)2 * NB * H4 * 4 + (size_t)2 * NB * HID * 4);
    float* vbuf = (float*)shared_base;

    size_t used = (size_t)(shared_base - (char*)d_ws);
    size_t avail = (ws_size > used) ? (ws_size - used) : 0;
    size_t maxc = avail / ((size_t)D5 * 4);
    if (maxc > (size_t)NPAIR0) maxc = NPAIR0;
    int chunk = ((int)maxc) & ~63;
    if (chunk < 512) chunk = 512;   // below this we cannot fit; assume ws suffices

    hipLaunchKernelGGL(init_kernel, dim3(NB), dim3(256), 0, stream,
                       hcur, ccur, pos, pair, rowlist0, rcount);
    hipLaunchKernelGGL(split_w, dim3(2048), dim3(256), 0, stream,
                       (const float4*)w_comp, w_hi, w_lo, (int)((size_t)D5 * H4 / 4));

    // ---- bidirectional LSTM, 16 sequential steps ----
    for (int t = 0; t < 16; ++t) {
        hipLaunchKernelGGL(gemm_lstm, dim3(32, 4, 2), dim3(256), 0, stream,
                           t, x, lens, w_ih_f, w_hh_f, w_ih_b, w_hh_b, hcur, gbuf);
        hipLaunchKernelGGL(lstm_gate, dim3(NB, 2), dim3(256), 0, stream,
                           t, lens, b_f, b_b, gbuf, hcur, ccur, h_hi, h_lo, c_seq);
    }

    // ---- iter 0: candidates + logits for all 15 pairs/batch (chunked) ----
    for (int off = 0; off < NPAIR0; off += chunk) {
        int rows = NPAIR0 - off; if (rows > chunk) rows = chunk;
        int mb = (rows + 63) >> 6;
        hipLaunchKernelGGL(gemm_pairs_mfma, dim3(mb, D5 / 128), dim3(256), 0, stream,
                           rowlist0 + off, rows, (const int*)nullptr,
                           h_hi, h_lo, w_hi, w_lo, vbuf);
        hipLaunchKernelGGL(gates_logits, dim3(rows), dim3(256), 0, stream,
                           rowlist0 + off, rows, (const int*)nullptr,
                           vbuf, b_comp, c_seq, w_q, nh, nc, logits);
    }

    // ---- 14 selection iterations (compacted incremental recompute) ----
    for (int it = 0; it < 14; ++it) {
        hipLaunchKernelGGL(merge_kernel, dim3(NB), dim3(256), 0, stream,
                           it, lens, c_seq, nh, nc, logits, pos, pair,
                           rowlist_inc, rcount + it, h_hi, h_lo);
        hipLaunchKernelGGL(gemm_pairs_mfma, dim3(8, D5 / 128), dim3(256), 0, stream,
                           rowlist_inc, 0, (const int*)(rcount + it),
                           h_hi, h_lo, w_hi, w_lo, vbuf);
        hipLaunchKernelGGL(gates_logits, dim3(512), dim3(256), 0, stream,
                           rowlist_inc, 0, (const int*)(rcount + it),
                           vbuf, b_comp, c_seq, w_q, nh, nc, logits);
    }
    hipLaunchKernelGGL(merge_kernel, dim3(NB), dim3(256), 0, stream,
                       14, lens, c_seq, nh, nc, logits, pos, pair,
                       rowlist_inc, rcount + 15, h_hi, h_lo);

    hipLaunchKernelGGL(copy_out, dim3(NB), dim3(256), 0, stream, h_hi, h_lo, out);
}